// Round 11
// baseline (817.071 us; speedup 1.0000x reference)
//
#include <hip/hip_runtime.h>
#include <hip/hip_bf16.h>

#define NN 50000
#define EE 800000
#define HD 64
#define LL 14
#define IND 128
#define OUTD 112
#define LN2 0.69314718056f

typedef __attribute__((ext_vector_type(8))) short short8;
typedef __attribute__((ext_vector_type(4))) float float4_;
typedef __attribute__((ext_vector_type(4))) unsigned short ushort4_;

__device__ __forceinline__ short bf16_hi(float x) {
    return (short)(__float_as_uint(x) >> 16);  // truncation split
}
__device__ __forceinline__ float bf16_f(short s) {
    return __uint_as_float(((unsigned)(unsigned short)s) << 16);
}
// round-to-nearest-even fp32 -> bf16 bits
__device__ __forceinline__ unsigned short f2b_rne(float x) {
    unsigned u = __float_as_uint(x);
    u += 0x7fffu + ((u >> 16) & 1u);
    return (unsigned short)(u >> 16);
}

// split 8 consecutive fp32 (16B-aligned) into bf16 hi/lo fragments
__device__ __forceinline__ void split8(const float* p, short8& hi, short8& lo) {
    float4_ a = *(const float4_*)p;
    float4_ b = *(const float4_*)(p + 4);
    float v[8] = {a[0], a[1], a[2], a[3], b[0], b[1], b[2], b[3]};
    #pragma unroll
    for (int j = 0; j < 8; ++j) {
        short h = bf16_hi(v[j]);
        hi[j] = h;
        lo[j] = bf16_hi(v[j] - bf16_f(h));
    }
}

// load B-fragment (8 k-rows of one 16-col slice) from global weights, hi/lo split
__device__ __forceinline__ void load_b(const float* __restrict__ W, int ldw,
                                       int colbase, int krow, short8& hi, short8& lo) {
    #pragma unroll
    for (int j = 0; j < 8; ++j) {
        float wv = W[(krow + j) * ldw + colbase];
        short h = bf16_hi(wv);
        hi[j] = h;
        lo[j] = bf16_hi(wv - bf16_f(h));
    }
}

// fp32-accurate product via 3 bf16 MFMAs (drop lo*lo)
__device__ __forceinline__ float4_ mm3(short8 ah, short8 al, short8 bh, short8 bl,
                                       float4_ acc) {
    acc = __builtin_amdgcn_mfma_f32_16x16x32_bf16(ah, bh, acc, 0, 0, 0);
    acc = __builtin_amdgcn_mfma_f32_16x16x32_bf16(al, bh, acc, 0, 0, 0);
    acc = __builtin_amdgcn_mfma_f32_16x16x32_bf16(ah, bl, acc, 0, 0, 0);
    return acc;
}

// ---------------- CSR build (padded to multiple of 4 per node) ----------------

__global__ void k_hist(const int* __restrict__ ei, int* __restrict__ cnt,
                       int* __restrict__ rank) {
    int e = blockIdx.x * blockDim.x + threadIdx.x;
    if (e < EE) rank[e] = atomicAdd(&cnt[ei[EE + e]], 1);
}

// exclusive scan over PADDED degrees
__global__ __launch_bounds__(1024) void k_scan1(const int* __restrict__ deg,
                                                int* __restrict__ excl,
                                                int* __restrict__ bsum) {
    __shared__ int ws[16];
    int tid = threadIdx.x, lane = tid & 63, w = tid >> 6;
    int gid = blockIdx.x * 1024 + tid;
    int v = (gid < NN) ? ((deg[gid] + 3) & ~3) : 0;
    int x = v;
    #pragma unroll
    for (int d = 1; d < 64; d <<= 1) {
        int y = __shfl_up(x, d);
        if (lane >= d) x += y;
    }
    if (lane == 63) ws[w] = x;
    __syncthreads();
    if (tid == 0) {
        int acc = 0;
        for (int i = 0; i < 16; i++) { int t = ws[i]; ws[i] = acc; acc += t; }
        bsum[blockIdx.x] = acc;
    }
    __syncthreads();
    if (gid < NN) excl[gid] = x - v + ws[w];
}

__global__ void k_scan2(const int* __restrict__ bsum, int* __restrict__ boff, int nb) {
    if (threadIdx.x == 0) {
        int acc = 0;
        for (int i = 0; i < nb; i++) { boff[i] = acc; acc += bsum[i]; }
        boff[nb] = acc;  // padded total
    }
}

// apply boff, fill pad slots with sentinel NN, zero sentinel P rows
__global__ __launch_bounds__(1024) void k_finish(int* __restrict__ rp,
                                                 const int* __restrict__ boff, int nb,
                                                 const int* __restrict__ deg,
                                                 int* __restrict__ csrc,
                                                 unsigned short* __restrict__ PA,
                                                 unsigned short* __restrict__ PB) {
    int gid = blockIdx.x * 1024 + threadIdx.x;
    if (gid < NN) {
        int base = rp[gid] + boff[blockIdx.x];
        rp[gid] = base;
        int d = deg[gid], pd = (d + 3) & ~3;
        for (int j = d; j < pd; ++j) csrc[base + j] = NN;
    }
    if (gid == 0) rp[NN] = boff[nb];
    if (blockIdx.x == 0 && threadIdx.x < 2 * HD) {
        int t = threadIdx.x;
        if (t < HD) PA[(size_t)NN * HD + t] = 0;
        else PB[(size_t)NN * HD + (t - HD)] = 0;
    }
}

__global__ void k_scatter(const int* __restrict__ ei, const int* __restrict__ rp,
                          const int* __restrict__ rank, int* __restrict__ csrc) {
    int e = blockIdx.x * blockDim.x + threadIdx.x;
    if (e < EE) {
        int d = ei[EE + e];
        csrc[rp[d] + rank[e]] = ei[e];
    }
}

// ---------------- Encoder: h0 = x @ enc_W + enc_b, plus P0 = bf16(exp(msg)) ----------------

__global__ __launch_bounds__(256) void k_enc(const float* __restrict__ x,
                                             const float* __restrict__ W,
                                             const float* __restrict__ b,
                                             float* __restrict__ h,
                                             unsigned short* __restrict__ P0) {
    __shared__ float X[16 * 132];
    int tid = threadIdx.x, lane = tid & 63, w = tid >> 6;
    int nb = blockIdx.x * 16;
    int nq = lane >> 4, nr = lane & 15;
    int colbase = w * 16 + nr;

    {
        const float* src = x + (size_t)nb * IND + tid * 8;
        float4_ a = *(const float4_*)src;
        float4_ c = *(const float4_*)(src + 4);
        int m = tid >> 4, k8 = 8 * (tid & 15);
        *(float4_*)&X[m * 132 + k8] = a;
        *(float4_*)&X[m * 132 + k8 + 4] = c;
    }
    __syncthreads();

    float4_ acc = {};
    #pragma unroll
    for (int t = 0; t < 4; ++t) {
        short8 ah, al, bh, bl;
        split8(&X[nr * 132 + t * 32 + nq * 8], ah, al);
        load_b(W, HD, colbase, t * 32 + nq * 8, bh, bl);
        acc = mm3(ah, al, bh, bl, acc);
    }

    float bias = b[colbase];
    #pragma unroll
    for (int r = 0; r < 4; ++r) {
        int node = nb + nq * 4 + r;
        float y = acc[r] + bias;
        h[node * HD + colbase] = y;
        float msg = fminf(fmaxf(y, 0.f) + 1e-7f, 50.f);
        P0[node * HD + colbase] = f2b_rne(__expf(msg));
    }
}

// 4-channel accumulate of one gathered P half-row pair
__device__ __forceinline__ void acc4(unsigned d0, unsigned d1,
                                     float& s0, float& s1, float& s2, float& s3,
                                     float& n0, float& n1, float& n2, float& n3) {
    float p0 = __uint_as_float(d0 << 16);
    float p1 = __uint_as_float(d0 & 0xffff0000u);
    float p2 = __uint_as_float(d1 << 16);
    float p3 = __uint_as_float(d1 & 0xffff0000u);
    s0 += p0; s1 += p1; s2 += p2; s3 += p3;
    n0 = fmaf(p0, __log2f(fmaxf(p0, 1e-20f)), n0);
    n1 = fmaf(p1, __log2f(fmaxf(p1, 1e-20f)), n1);
    n2 = fmaf(p2, __log2f(fmaxf(p2, 1e-20f)), n2);
    n3 = fmaf(p3, __log2f(fmaxf(p3, 1e-20f)), n3);
}

// ---------------- GENConv layer: pair-interleaved quarter-wave P-gather
//                  + MFMA matmul + residual + fused prenorm ----------------

__global__ __launch_bounds__(256) void k_layer(const unsigned short* __restrict__ Pin,
                                               const float* __restrict__ selfh,  // layer0 only
                                               const float* __restrict__ hres,
                                               float* __restrict__ hout,
                                               unsigned short* __restrict__ Pout,
                                               const int* __restrict__ rp,
                                               const int* __restrict__ csrc,
                                               const float* __restrict__ W,
                                               const float* __restrict__ b,
                                               const float* __restrict__ gnext,
                                               const float* __restrict__ bnext) {
    __shared__ float T[16 * 68];
    int tid = threadIdx.x, lane = tid & 63, w = tid >> 6;
    int nb = blockIdx.x * 16;
    int nq = lane >> 4, nr = lane & 15;
    int colbase = w * 16 + nr;

    // B fragments, register-resident
    short8 Bhi[2], Blo[2];
    #pragma unroll
    for (int t = 0; t < 2; ++t)
        load_b(W, HD, colbase, t * 32 + nq * 8, Bhi[t], Blo[t]);

    // quarter-wave gather, two nodes interleaved: group g owns edge k*4+g;
    // lane covers channels ci*4..ci*4+3. Padded CSR (pads -> zero-row NN).
    int g = lane >> 4;
    int ci = lane & 15;
    int base4 = rp[nb + w * 4];
    #pragma unroll 1
    for (int i = 0; i < 4; i += 2) {
        int nodeA = nb + w * 4 + i;
        int begA = (i == 0) ? base4 : rp[nodeA];
        int midB = rp[nodeA + 1];
        int endB = rp[nodeA + 2];
        int nkA = (midB - begA) >> 2;
        int nkB = (endB - midB) >> 2;
        const int* epA = csrc + begA + g;
        const int* epB = csrc + midB + g;
        float sA0 = 0.f, sA1 = 0.f, sA2 = 0.f, sA3 = 0.f;
        float nA0 = 0.f, nA1 = 0.f, nA2 = 0.f, nA3 = 0.f;
        float sB0 = 0.f, sB1 = 0.f, sB2 = 0.f, sB3 = 0.f;
        float nB0 = 0.f, nB1 = 0.f, nB2 = 0.f, nB3 = 0.f;
        int kc = min(nkA, nkB);
        #pragma unroll 2
        for (int k = 0; k < kc; ++k) {
            int srcA = epA[k * 4];
            int srcB = epB[k * 4];
            const unsigned* ppA = (const unsigned*)(Pin + ((size_t)srcA << 6)) + ci * 2;
            const unsigned* ppB = (const unsigned*)(Pin + ((size_t)srcB << 6)) + ci * 2;
            unsigned a0 = ppA[0], a1 = ppA[1];
            unsigned b0 = ppB[0], b1 = ppB[1];
            acc4(a0, a1, sA0, sA1, sA2, sA3, nA0, nA1, nA2, nA3);
            acc4(b0, b1, sB0, sB1, sB2, sB3, nB0, nB1, nB2, nB3);
        }
        #pragma unroll 2
        for (int k = kc; k < nkA; ++k) {
            int srcA = epA[k * 4];
            const unsigned* ppA = (const unsigned*)(Pin + ((size_t)srcA << 6)) + ci * 2;
            unsigned a0 = ppA[0], a1 = ppA[1];
            acc4(a0, a1, sA0, sA1, sA2, sA3, nA0, nA1, nA2, nA3);
        }
        #pragma unroll 2
        for (int k = kc; k < nkB; ++k) {
            int srcB = epB[k * 4];
            const unsigned* ppB = (const unsigned*)(Pin + ((size_t)srcB << 6)) + ci * 2;
            unsigned b0 = ppB[0], b1 = ppB[1];
            acc4(b0, b1, sB0, sB1, sB2, sB3, nB0, nB1, nB2, nB3);
        }
        // reduce both nodes across the 4 quarter-wave groups (lane bits 4,5)
        #pragma unroll
        for (int d = 16; d < 64; d <<= 1) {
            sA0 += __shfl_xor(sA0, d); sA1 += __shfl_xor(sA1, d);
            sA2 += __shfl_xor(sA2, d); sA3 += __shfl_xor(sA3, d);
            nA0 += __shfl_xor(nA0, d); nA1 += __shfl_xor(nA1, d);
            nA2 += __shfl_xor(nA2, d); nA3 += __shfl_xor(nA3, d);
            sB0 += __shfl_xor(sB0, d); sB1 += __shfl_xor(sB1, d);
            sB2 += __shfl_xor(sB2, d); sB3 += __shfl_xor(sB3, d);
            nB0 += __shfl_xor(nB0, d); nB1 += __shfl_xor(nB1, d);
            nB2 += __shfl_xor(nB2, d); nB3 += __shfl_xor(nB3, d);
        }
        if (g == 0) {
            #pragma unroll
            for (int q = 0; q < 2; ++q) {
                int node = nb + w * 4 + i + q;
                float r0 = q ? sB0 : sA0, r1 = q ? sB1 : sA1;
                float r2 = q ? sB2 : sA2, r3 = q ? sB3 : sA3;
                float m0 = q ? nB0 : nA0, m1 = q ? nB1 : nA1;
                float m2 = q ? nB2 : nA2, m3 = q ? nB3 : nA3;
                float a0 = LN2 * m0 / fmaxf(r0, 1e-16f);
                float a1 = LN2 * m1 / fmaxf(r1, 1e-16f);
                float a2 = LN2 * m2 / fmaxf(r2, 1e-16f);
                float a3 = LN2 * m3 / fmaxf(r3, 1e-16f);
                float4_ xv;
                if (selfh) {
                    float4_ sf = *(const float4_*)&selfh[(size_t)node * HD + ci * 4];
                    xv[0] = sf[0] + a0; xv[1] = sf[1] + a1;
                    xv[2] = sf[2] + a2; xv[3] = sf[3] + a3;
                } else {
                    const unsigned* pp =
                        (const unsigned*)(Pin + ((size_t)node << 6)) + ci * 2;
                    unsigned d0 = pp[0], d1 = pp[1];
                    xv[0] = LN2 * __log2f(__uint_as_float(d0 << 16)) - 1e-7f + a0;
                    xv[1] = LN2 * __log2f(__uint_as_float(d0 & 0xffff0000u)) - 1e-7f + a1;
                    xv[2] = LN2 * __log2f(__uint_as_float(d1 << 16)) - 1e-7f + a2;
                    xv[3] = LN2 * __log2f(__uint_as_float(d1 & 0xffff0000u)) - 1e-7f + a3;
                }
                *(float4_*)&T[(w * 4 + i + q) * 68 + ci * 4] = xv;
            }
        }
    }
    __syncthreads();

    short8 Ahi[2], Alo[2];
    #pragma unroll
    for (int t = 0; t < 2; ++t)
        split8(&T[nr * 68 + t * 32 + nq * 8], Ahi[t], Alo[t]);
    __syncthreads();  // all A reads done before T is overwritten

    float4_ acc = {};
    #pragma unroll
    for (int t = 0; t < 2; ++t)
        acc = mm3(Ahi[t], Alo[t], Bhi[t], Blo[t], acc);

    float bias = b[colbase];
    #pragma unroll
    for (int r = 0; r < 4; ++r) {
        int m = nq * 4 + r;
        int node = nb + m;
        float v = acc[r] + bias;
        if (hres) v += hres[node * HD + colbase];
        hout[node * HD + colbase] = v;
        T[m * 68 + colbase] = v;
    }
    if (!Pout) return;
    __syncthreads();

    // LN phase: thread -> node tid>>4, 4 channels; emit P = bf16(exp(msg))
    int m = tid >> 4, c4 = (tid & 15) * 4;
    float4_ vv = *(const float4_*)&T[m * 68 + c4];
    float ps_ = (vv[0] + vv[1]) + (vv[2] + vv[3]);
    float pq_ = (vv[0] * vv[0] + vv[1] * vv[1]) + (vv[2] * vv[2] + vv[3] * vv[3]);
    #pragma unroll
    for (int d = 8; d; d >>= 1) {
        ps_ += __shfl_xor(ps_, d);
        pq_ += __shfl_xor(pq_, d);
    }
    float mu = ps_ * (1.f / 64.f);
    float var = pq_ * (1.f / 64.f) - mu * mu;
    float inv = rsqrtf(fmaxf(var, 0.f) + 1e-5f);
    float4_ g4 = *(const float4_*)&gnext[c4];
    float4_ b4 = *(const float4_*)&bnext[c4];
    ushort4_ po;
    #pragma unroll
    for (int j = 0; j < 4; ++j) {
        float y = fmaxf((vv[j] - mu) * inv * g4[j] + b4[j], 0.f);
        float msg = fminf(y + 1e-7f, 50.f);
        po[j] = f2b_rne(__expf(msg));
    }
    *(ushort4_*)&Pout[(nb + m) * HD + c4] = po;
}

// ---------------- Predictor: out = h @ pred_W + pred_b  (MFMA) ----------------

__global__ __launch_bounds__(256) void k_pred(const float* __restrict__ h,
                                              const float* __restrict__ W,
                                              const float* __restrict__ b,
                                              float* __restrict__ out) {
    __shared__ float T[16 * 68];
    int tid = threadIdx.x, lane = tid & 63, w = tid >> 6;
    int nb = blockIdx.x * 16;
    int nq = lane >> 4, nr = lane & 15;

    {
        const float* src = h + (size_t)nb * HD + tid * 4;
        float4_ a = *(const float4_*)src;
        int m = tid >> 4, k4 = 4 * (tid & 15);
        *(float4_*)&T[m * 68 + k4] = a;
    }
    __syncthreads();

    short8 Ahi[2], Alo[2];
    #pragma unroll
    for (int t = 0; t < 2; ++t)
        split8(&T[nr * 68 + t * 32 + nq * 8], Ahi[t], Alo[t]);

    for (int tt = w; tt < 7; tt += 4) {
        int colbase = tt * 16 + nr;
        float4_ acc = {};
        #pragma unroll
        for (int t = 0; t < 2; ++t) {
            short8 bh, bl;
            load_b(W, OUTD, colbase, t * 32 + nq * 8, bh, bl);
            acc = mm3(Ahi[t], Alo[t], bh, bl, acc);
        }
        float bias = b[colbase];
        #pragma unroll
        for (int r = 0; r < 4; ++r) {
            int node = nb + nq * 4 + r;
            out[node * OUTD + colbase] = acc[r] + bias;
        }
    }
}

// ---------------- Launch ----------------

extern "C" void kernel_launch(void* const* d_in, const int* in_sizes, int n_in,
                              void* d_out, int out_size, void* d_ws, size_t ws_size,
                              hipStream_t stream) {
    const float* x    = (const float*)d_in[0];
    const int*   ei   = (const int*)d_in[1];
    const float* encW = (const float*)d_in[2];
    const float* encb = (const float*)d_in[3];
    const float* lng  = (const float*)d_in[4];
    const float* lnb  = (const float*)d_in[5];
    const float* mlpW = (const float*)d_in[6];
    const float* mlpb = (const float*)d_in[7];
    const float* pW   = (const float*)d_in[8];
    const float* pb   = (const float*)d_in[9];
    float* out = (float*)d_out;

    float* hA  = (float*)d_ws;
    float* hB  = hA + (size_t)NN * HD;
    unsigned short* PA = (unsigned short*)(hB + (size_t)NN * HD);       // (NN+1) rows
    unsigned short* PB = PA + (size_t)(NN + 1) * HD;                    // (NN+1) rows
    int* rp   = (int*)(PB + (size_t)(NN + 1) * HD);
    int* cnt  = rp + (NN + 1);
    int* csrc = cnt + NN;            // padded capacity: EE + 3*NN + 64
    int* rank = csrc + (EE + 3 * NN + 64);
    int* bsum = rank + EE;
    int* boff = bsum + 64;

    // CSR build (per call; ws is re-poisoned each launch)
    hipMemsetAsync(cnt, 0, NN * sizeof(int), stream);
    k_hist<<<(EE + 255) / 256, 256, 0, stream>>>(ei, cnt, rank);
    const int NB = (NN + 1023) / 1024;  // 49
    k_scan1<<<NB, 1024, 0, stream>>>(cnt, rp, bsum);
    k_scan2<<<1, 64, 0, stream>>>(bsum, boff, NB);
    k_finish<<<NB, 1024, 0, stream>>>(rp, boff, NB, cnt, csrc, PA, PB);
    k_scatter<<<(EE + 255) / 256, 256, 0, stream>>>(ei, rp, rank, csrc);

    // Encoder -> h_0 in hA, P_0 in PA
    k_enc<<<NN / 16, 256, 0, stream>>>(x, encW, encb, hA, PA);

    // Layer 0: self term = raw h0; writes h_1 -> hB, P_1 -> PB
    k_layer<<<NN / 16, 256, 0, stream>>>(PA, hA, nullptr, hB, PB, rp, csrc,
                                         mlpW, mlpb, lng, lnb);

    float* hres = hB;   // h_1
    float* hdst = hA;
    unsigned short* pc = PB;
    unsigned short* pn = PA;
    for (int l = 1; l < LL; ++l) {
        bool last = (l == LL - 1);
        k_layer<<<NN / 16, 256, 0, stream>>>(pc, nullptr, hres, hdst,
                                             last ? nullptr : pn,
                                             rp, csrc,
                                             mlpW + (size_t)l * HD * HD,
                                             mlpb + (size_t)l * HD,
                                             last ? nullptr : lng + (size_t)l * HD,
                                             last ? nullptr : lnb + (size_t)l * HD);
        float* t = hres; hres = hdst; hdst = t;
        unsigned short* u = pc; pc = pn; pn = u;
    }

    // Predictor on h_14
    k_pred<<<NN / 16, 256, 0, stream>>>(hres, pW, pb, out);
}